// Round 5
// baseline (6436.042 us; speedup 1.0000x reference)
//
#include <hip/hip_runtime.h>
#include <cstdint>
#include <cstddef>

typedef unsigned int u32;
typedef unsigned long long u64;
typedef unsigned short u16;

#define BBOX_CLAMP 4.135166556742356f

__device__ __forceinline__ u32 fkey(float f){
  u32 b = __float_as_uint(f);
  return (b & 0x80000000u) ? ~b : (b | 0x80000000u);
}
__device__ __forceinline__ float keyinv(u32 k){
  u32 b = (k & 0x80000000u) ? (k & 0x7FFFFFFFu) : ~k;
  return __uint_as_float(b);
}
__device__ __forceinline__ u64 lanemask_lt(int lane){
  return lane ? (~0ull >> (64-lane)) : 0ull;
}

struct ConvTab {
  const float* fm[5];
  int H[5], W[5], TX[5], base[5], loff[5], szl[5];
};
struct PriTab { const float* p[5]; };
struct RoiTab { const float* fm[4]; int H[4], W[4]; float inv[4]; };
struct SelDesc { int key_off, size, k, cand_off, cand_cap, cnt_idx, sel_off; };
struct SelTab { SelDesc d[11]; };

// ------------------------------------------------------------------ prep
__global__ __launch_bounds__(256) void prep_wt_k(const float* w, float* wT){
  int g = blockIdx.x*256 + threadIdx.x;
  if (g >= 2304*256) return;
  int c = g & 255, t2 = g >> 8;
  int e = t2 % 9, ci = t2 / 9;
  wT[g] = w[c*2304 + ci*9 + e];   // wT[(ci*9+e)*256 + c]
}
__global__ __launch_bounds__(256) void prep_wcat_k(const float* clsw, const float* clsb,
                                                   const float* bregw, const float* bregb,
                                                   float* WCAT, float* BCAT){
  int g = blockIdx.x*256 + threadIdx.x;
  if (g < 401*1024){
    int nr = g >> 10, k = g & 1023;
    WCAT[g] = (nr < 81) ? clsw[nr*1024 + k] : bregw[(nr-81)*1024 + k];
  }
  if (g < 401) BCAT[g] = (g < 81) ? clsb[g] : bregb[g-81];
}

// ------------------------------------------------------------------ fused RPN conv3x3+relu+1x1 heads
__global__ __launch_bounds__(256,2) void rpn_fused_k(ConvTab ct, const float* wT, const float* convb,
    const float* logw, const float* logb, const float* regw, const float* regb,
    float* LOGIT, float* REGB){
  __shared__ float sIn[4][3][28];
  __shared__ float sX[256][29];
  __shared__ float sW1[15][257];
  __shared__ float sB1[16];
  int bid = blockIdx.x;
  int lv = 0;
  #pragma unroll
  for (int l=1; l<5; l++) if (bid >= ct.base[l]) lv = l;
  int rem = bid - ct.base[lv];
  int H = ct.H[lv], W = ct.W[lv], TX = ct.TX[lv];
  int perimg = H * TX;
  int img = rem / perimg; rem -= img*perimg;
  int y = rem / TX;
  int x0 = (rem - y*TX) * 26;
  int tid = threadIdx.x;
  for (int t=tid; t<15*256; t+=256) sW1[t>>8][t&255] = (t < 768) ? logw[t] : regw[t-768];
  if (tid < 15) sB1[tid] = (tid < 3) ? logb[tid] : regb[tid-3];
  const float* fm = ct.fm[lv] + (size_t)img*256*H*W;
  float bias = convb[tid];
  float acc[26];
  #pragma unroll
  for (int t=0;t<26;t++) acc[t] = bias;
  for (int cib=0; cib<64; cib++){
    __syncthreads();
    for (int t=tid; t<336; t+=256){
      int cc = t/84, rm = t - cc*84;
      int row = rm/28, col = rm - row*28;
      int gy = y + row - 1, gx = x0 + col - 1;
      float v = 0.f;
      if (gy >= 0 && gy < H && gx >= 0 && gx < W)
        v = fm[(size_t)(cib*4+cc)*H*W + gy*W + gx];
      sIn[cc][row][col] = v;
    }
    __syncthreads();
    #pragma unroll
    for (int c4=0; c4<4; c4++){
      int ci = cib*4 + c4;
      float wv[9];
      #pragma unroll
      for (int e=0;e<9;e++) wv[e] = wT[(ci*9+e)*256 + tid];
      #pragma unroll
      for (int ky=0; ky<3; ky++){
        const float4* rp = (const float4*)&sIn[c4][ky][0];
        float rr[28];
        #pragma unroll
        for (int u=0;u<7;u++){ float4 q = rp[u]; rr[u*4]=q.x; rr[u*4+1]=q.y; rr[u*4+2]=q.z; rr[u*4+3]=q.w; }
        #pragma unroll
        for (int kx=0; kx<3; kx++){
          float wg = wv[ky*3+kx];
          #pragma unroll
          for (int t=0;t<26;t++) acc[t] = fmaf(rr[t+kx], wg, acc[t]);
        }
      }
    }
  }
  __syncthreads();
  #pragma unroll
  for (int t=0;t<26;t++) sX[tid][t] = fmaxf(acc[t], 0.f);
  __syncthreads();
  int base = ct.loff[lv] + img*ct.szl[lv];
  for (int p=tid; p<390; p+=256){
    int o = p/26, t = p - o*26;
    int x = x0 + t;
    if (x < W){
      float s = sB1[o];
      #pragma unroll 8
      for (int cc=0; cc<256; cc++) s = fmaf(sX[cc][t], sW1[o][cc], s);
      int pos = y*W + x;
      if (o < 3) LOGIT[base + pos*3 + o] = s;
      else {
        int rc = o - 3;
        REGB[(size_t)(base + pos*3 + (rc>>2))*4 + (rc&3)] = s;
      }
    }
  }
}

// ------------------------------------------------------------------ top-k machinery (histogram radix select)
__global__ __launch_bounds__(256) void keygen1_k(const float* LOGIT, u32* KEY1){
  int g = blockIdx.x*256 + threadIdx.x;
  if (g < 212784) KEY1[g] = fkey(LOGIT[g]);
}

__global__ __launch_bounds__(256) void hist_k(const u32* keys, u32* HIST, const u32* SCANB,
                                              SelTab st, int dbase, int pass){
  int listI = dbase + blockIdx.y;
  SelDesc d = st.d[listI];
  __shared__ u32 lh[4096];
  int tid = threadIdx.x;
  for (int t=tid; t<4096; t+=256) lh[t]=0;
  __syncthreads();
  int start = blockIdx.x*4096;
  u32 b1 = (pass==2) ? SCANB[listI*16+0] : 0;
  int end = min(start+4096, d.size);
  for (int t=start+tid; t<end; t+=256){
    u32 k = keys[d.key_off + t];
    if (!k) continue;
    if (pass==1) atomicAdd(&lh[k>>20], 1u);
    else if ((k>>20)==b1) atomicAdd(&lh[(k>>8)&0xFFFu], 1u);
  }
  __syncthreads();
  for (int t=tid; t<4096; t+=256){ u32 v=lh[t]; if (v) atomicAdd(&HIST[listI*4096+t], v); }
}

__global__ __launch_bounds__(256) void scan_k(const u32* HIST, u32* SCANB, SelTab st, int dbase, int pass){
  int listI = dbase + blockIdx.x;
  SelDesc d = st.d[listI];
  const u32* h = &HIST[(size_t)listI*4096];
  __shared__ u32 csum[256];
  __shared__ u32 sh_kwant;
  int tid = threadIdx.x;
  u32 loc[16]; u32 lsum = 0;
  #pragma unroll
  for (int u=0; u<16; u++){ loc[u] = h[tid*16+u]; lsum += loc[u]; }
  csum[tid] = lsum;
  __syncthreads();
  if (tid==0){
    u32 suf = 0;
    for (int t=255; t>=0; t--){ u32 c = csum[t]; csum[t] = suf; suf += c; }
    u32 total = suf;
    u32 kwant;
    if (pass==1){
      kwant = min((u32)d.k, total);
      SCANB[listI*16+2] = kwant;
      if (kwant==0){ SCANB[listI*16+0]=0xFFFFFFFFu; SCANB[listI*16+1]=0; SCANB[listI*16+3]=0x01000000u; }
    } else {
      u32 keff = SCANB[listI*16+2];
      kwant = (keff==0) ? 0 : (keff - SCANB[listI*16+1]);
    }
    sh_kwant = kwant;
  }
  __syncthreads();
  u32 kwant = sh_kwant;
  if (kwant){
    u32 cum = csum[tid];
    #pragma unroll
    for (int u=15; u>=0; u--){
      u32 cnt = loc[u];
      if (cnt && cum < kwant && cum + cnt >= kwant){
        u32 bin = (u32)(tid*16 + u);
        if (pass==1){ SCANB[listI*16+0] = bin; SCANB[listI*16+1] = cum; }
        else        { SCANB[listI*16+3] = (SCANB[listI*16+0]<<12) | bin; }
      }
      cum += cnt;
    }
  }
}

__global__ __launch_bounds__(256) void compact_k(const u32* keys, const u32* SCANB,
                                                 u64* CAND, u32* CNT, SelTab st, int dbase){
  int listI = dbase + blockIdx.y;
  SelDesc d = st.d[listI];
  u32 thr = SCANB[listI*16+3];
  int start = blockIdx.x*4096;
  int end = min(start+4096, d.size);
  for (int t=start+threadIdx.x; t<end; t+=256){
    u32 k = keys[d.key_off + t];
    if (k && (k>>8) >= thr){
      u32 slot = atomicAdd(&CNT[d.cnt_idx], 1u);
      if (slot < (u32)d.cand_cap)
        CAND[d.cand_off + slot] = ((u64)k << 32) | (u32)(~(u32)t);
    }
  }
}

// static 64KB LDS (cap<=8192) — no dynamic-shared attribute call needed (graph-capture safe)
__global__ __launch_bounds__(256) void sort_k(const u64* CAND, const u32* CNT, u64* SEL,
                                              SelTab st, int dbase){
  __shared__ u64 sa[8192];
  SelDesc d = st.d[dbase + blockIdx.x];
  int cap = d.cand_cap;
  int tid = threadIdx.x;
  u32 cnt = min(CNT[d.cnt_idx], (u32)cap);
  for (int t=tid; t<cap; t+=256) sa[t] = (t < (int)cnt) ? CAND[d.cand_off + t] : 0ull;
  __syncthreads();
  for (int kk=2; kk<=cap; kk<<=1){
    for (int j=kk>>1; j>0; j>>=1){
      for (int t=tid; t<cap; t+=256){
        int l = t ^ j;
        if (l > t){
          u64 x = sa[t], y = sa[l];
          bool asc = ((t & kk) == 0);
          if ((x > y) == asc){ sa[t]=y; sa[l]=x; }
        }
      }
      __syncthreads();
    }
  }
  for (int r=tid; r<d.k; r+=256) SEL[d.sel_off + r] = sa[cap-1-r];
}

// ------------------------------------------------------------------ stage1 decode + NMS + merge
__global__ __launch_bounds__(256) void decode1_k(const u64* SEL, const float* LOGIT, const float* REGB,
    PriTab pt, const int* imsz, SelTab st, float* BOX1, float* SC1){
  int g = blockIdx.x*256 + threadIdx.x;
  if (g >= 10240) return;
  int list = g >> 10, r = g & 1023;
  SelDesc d = st.d[list];
  if (r >= d.k) return;
  int lv = list >> 1, img = list & 1;
  u64 e = SEL[list*1024 + r];
  u32 idx = ~((u32)e);
  float logit = LOGIT[d.key_off + idx];
  SC1[list*1024 + r] = 1.f/(1.f + expf(-logit));
  const float* rg = &REGB[(size_t)(d.key_off + idx)*4];
  const float* pr = &pt.p[lv][(size_t)idx*4];
  float pw = pr[2]-pr[0], ph = pr[3]-pr[1];
  float pcx = pr[0]+0.5f*pw, pcy = pr[1]+0.5f*ph;
  float cx = pcx + rg[0]*pw;
  float cy = pcy + rg[1]*ph;
  float w  = pw * expf(fminf(rg[2], BBOX_CLAMP));
  float h  = ph * expf(fminf(rg[3], BBOX_CLAMP));
  float Wc = (float)imsz[img*2+1], Hc = (float)imsz[img*2+0];
  float x1 = fminf(fmaxf(cx-0.5f*w, 0.f), Wc);
  float y1 = fminf(fmaxf(cy-0.5f*h, 0.f), Hc);
  float x2 = fminf(fmaxf(cx+0.5f*w, 0.f), Wc);
  float y2 = fminf(fmaxf(cy+0.5f*h, 0.f), Hc);
  float4 b = make_float4(x1,y1,x2,y2);
  *(float4*)&BOX1[(size_t)(list*1024+r)*4] = b;
}

__global__ __launch_bounds__(256) void nms_mat1_k(const float* BOX1, u64* MAT1){
  int list = blockIdx.y;
  int lv = list >> 1, img = list & 1;
  int kl = (lv==4) ? 312 : 1000;
  __shared__ float4 sb[1024];
  int tid = threadIdx.x;
  float off = (float)(img*10+lv) * 4096.0f;
  for (int t=tid; t<1024; t+=256){
    if (t < kl){
      float4 b = *(const float4*)&BOX1[(size_t)(list*1024+t)*4];
      b.x += off; b.y += off; b.z += off; b.w += off;
      sb[t] = b;
    } else sb[t] = make_float4(0,0,0,0);
  }
  __syncthreads();
  int i = blockIdx.x*16 + (tid>>4);
  int w = tid & 15;
  if (i >= kl) return;
  float4 bi = sb[i];
  float ai = (bi.z-bi.x)*(bi.w-bi.y);
  u64 bits = 0;
  #pragma unroll 4
  for (int u=0; u<64; u++){
    int j = w*64 + u;
    if (j > i && j < kl){
      float4 bj = sb[j];
      float aj = (bj.z-bj.x)*(bj.w-bj.y);
      float lx = fmaxf(bi.x,bj.x), ly = fmaxf(bi.y,bj.y);
      float rx = fminf(bi.z,bj.z), ry = fminf(bi.w,bj.w);
      float iw = fmaxf(rx-lx,0.f), ih = fmaxf(ry-ly,0.f);
      float inter = iw*ih;
      float iou = inter / fmaxf(ai+aj-inter, 1e-9f);
      if (iou > 0.7f) bits |= (1ull<<u);
    }
  }
  MAT1[(size_t)(list*1024+i)*16 + w] = bits;
}

__global__ __launch_bounds__(64) void nms_scan1_k(const u64* MAT1, u64* KEEPM){
  int list = blockIdx.x, lane = threadIdx.x;
  int lv = list >> 1;
  int kl = (lv==4) ? 312 : 1000;
  int rem = kl - lane*64;
  u64 aw = (rem >= 64) ? ~0ull : (rem > 0 ? ((1ull<<rem)-1ull) : 0ull);
  const u64* rows = MAT1 + (size_t)list*1024*16;
#define LDR1(p) ((lane<16 && (p)<kl) ? rows[(size_t)(p)*16 + lane] : 0ull)
  u64 q0=LDR1(0),q1=LDR1(1),q2=LDR1(2),q3=LDR1(3),q4=LDR1(4),q5=LDR1(5),q6=LDR1(6),q7=LDR1(7);
  for (int i=0; i<kl; i++){
    u64 cur = q0; q0=q1; q1=q2; q2=q3; q3=q4; q4=q5; q5=q6; q6=q7; q7=LDR1(i+8);
    u64 wv = __shfl(aw, i>>6, 64);
    bool alive = (wv >> (i & 63)) & 1ull;
    aw &= ~(alive ? cur : 0ull);
  }
#undef LDR1
  if (lane < 16) KEEPM[list*16 + lane] = aw;
}

__global__ __launch_bounds__(64) void kprefix_k(const u64* KEEPM, u32* KPRE){
  int list = blockIdx.x, lane = threadIdx.x;
  u32 base = 0;
  for (int ch=0; ch<16; ch++){
    u64 m = KEEPM[list*16 + ch];
    u32 below = (u32)__popcll(m & lanemask_lt(lane));
    KPRE[list*1056 + ch*64 + lane] = base + below;
    base += (u32)__popcll(m);
  }
  if (lane==0) KPRE[list*1056 + 1024] = base;
}

__global__ __launch_bounds__(256) void merge_k(const u64* KEEPM, const u32* KPRE, const float* SC1,
    const float* BOX1, float* PROPS, u32* PVALID){
  int g = blockIdx.x*256 + threadIdx.x;
  if (g >= 10240) return;
  int list = g >> 10, r = g & 1023;
  int lv = list >> 1, img = list & 1;
  int kl = (lv==4) ? 312 : 1000;
  if (r >= kl) return;
  if (!((KEEPM[list*16 + (r>>6)] >> (r & 63)) & 1ull)) return;
  float s = SC1[list*1024 + r];
  u32 pos = KPRE[list*1056 + r];
  #pragma unroll
  for (int lv2=0; lv2<5; lv2++){
    if (lv2 == lv) continue;
    int l2 = lv2*2 + img;
    int k2 = (lv2==4) ? 312 : 1000;
    int lo = 0, hi = k2;
    while (lo < hi){
      int mid = (lo+hi) >> 1;
      float sj = SC1[l2*1024 + mid];
      bool before = (sj > s) || (sj == s && lv2 < lv);
      if (before) lo = mid+1; else hi = mid;
    }
    pos += KPRE[l2*1056 + lo];
  }
  if (pos < 1000){
    int dst = img*1000 + pos;
    *(float4*)&PROPS[(size_t)dst*4] = *(const float4*)&BOX1[(size_t)(list*1024+r)*4];
    PVALID[dst] = 1;
  }
}

// ------------------------------------------------------------------ ROI align (thread = channel), chunked via rbase
__global__ __launch_bounds__(256) void roi_align_k(RoiTab rt, const float* PROPS, float* FEATC, int rbase){
  int r = rbase + blockIdx.x;
  int c = threadIdx.x;
  float4 bx = *(const float4*)&PROPS[(size_t)r*4];
  float area = fmaxf((bx.z-bx.x)*(bx.w-bx.y), 1e-6f);
  float fl = floorf(4.0f + log2f(sqrtf(area)/224.0f));
  int lvl = (int)(fminf(fmaxf(fl, 2.0f), 5.0f)) - 2;
  int H = rt.H[lvl], W = rt.W[lvl];
  float sc = rt.inv[lvl];
  const float* fm = rt.fm[lvl] + ((size_t)(r/1000)*256 + c)*(size_t)H*W;
  __shared__ int iy0[14], iy1[14], jx0[14], jx1[14];
  __shared__ float fly[14], flx[14];
  __shared__ int oy[14], ox[14];
  if (c < 28){
    int j = c % 14;
    bool isx = c >= 14;
    float b1 = isx ? bx.x : bx.y;
    float b2 = isx ? bx.z : bx.w;
    int lim = isx ? W : H;
    float t1 = b1*sc - 0.5f;
    float bwd = (b2*sc - 0.5f - t1) / 7.0f;
    float g = ((float)j + 0.5f) * 0.5f;
    float p = t1 + g*bwd;
    int oob = (p < -1.0f) || (p > (float)lim);
    float pc = fminf(fmaxf(p, 0.f), (float)(lim-1));
    int p0 = (int)floorf(pc);
    int p1 = min(p0+1, lim-1);
    float lp = pc - (float)p0;
    if (isx){ jx0[j]=p0; jx1[j]=p1; flx[j]=lp; ox[j]=oob; }
    else    { iy0[j]=p0; iy1[j]=p1; fly[j]=lp; oy[j]=oob; }
  }
  __syncthreads();
  float* fout = &FEATC[(size_t)blockIdx.x*12544 + c*49];
  #pragma unroll
  for (int pi=0; pi<7; pi++){
    #pragma unroll
    for (int pj=0; pj<7; pj++){
      float s = 0.f;
      #pragma unroll
      for (int di=0; di<2; di++){
        #pragma unroll
        for (int dj=0; dj<2; dj++){
          int i = pi*2+di, j = pj*2+dj;
          if (!(oy[i] | ox[j])){
            int y0=iy0[i], y1=iy1[i], x0=jx0[j], x1=jx1[j];
            float ly=fly[i], lx=flx[j];
            float v00 = fm[(size_t)y0*W + x0], v01 = fm[(size_t)y0*W + x1];
            float v10 = fm[(size_t)y1*W + x0], v11 = fm[(size_t)y1*W + x1];
            s += v00*(1-ly)*(1-lx) + v01*(1-ly)*lx + v10*ly*(1-lx) + v11*ly*lx;
          }
        }
      }
      fout[pi*7+pj] = s*0.25f;
    }
  }
}

// ------------------------------------------------------------------ f32 GEMM, parameterized split-K scratch stride
__global__ __launch_bounds__(256,2) void gemm_k(const float* A, int lda, int M,
                                                const float* B, int ldb, int N,
                                                float* Cp, int ldc, int Kc, int tilesM, int mstr){
  __shared__ float As[16][132];
  __shared__ float Bs[16][132];
  int tid = threadIdx.x;
  int bx = blockIdx.x;
  int tm0 = (bx % tilesM)*128;
  int tn0 = (bx / tilesM)*128;
  int k0 = blockIdx.y * Kc;
  int tmr = tid >> 4, tnr = tid & 15;
  int lr = tid >> 2, lq = tid & 3;
  float acc[8][8];
  #pragma unroll
  for (int i=0;i<8;i++){
    #pragma unroll
    for (int j=0;j<8;j++) acc[i][j] = 0.f;
  }
  const float4 z4 = make_float4(0,0,0,0);
  for (int kk=0; kk<Kc; kk+=16){
    int kb = k0 + kk + lq*4;
    int ar0 = tm0 + lr, ar1 = tm0 + lr + 64;
    float4 a0 = (ar0 < M) ? *(const float4*)&A[(size_t)ar0*lda + kb] : z4;
    float4 a1 = (ar1 < M) ? *(const float4*)&A[(size_t)ar1*lda + kb] : z4;
    int br0 = tn0 + lr, br1 = tn0 + lr + 64;
    float4 b0 = (br0 < N) ? *(const float4*)&B[(size_t)br0*ldb + kb] : z4;
    float4 b1 = (br1 < N) ? *(const float4*)&B[(size_t)br1*ldb + kb] : z4;
    __syncthreads();
    As[lq*4+0][lr] = a0.x; As[lq*4+1][lr] = a0.y; As[lq*4+2][lr] = a0.z; As[lq*4+3][lr] = a0.w;
    As[lq*4+0][lr+64] = a1.x; As[lq*4+1][lr+64] = a1.y; As[lq*4+2][lr+64] = a1.z; As[lq*4+3][lr+64] = a1.w;
    Bs[lq*4+0][lr] = b0.x; Bs[lq*4+1][lr] = b0.y; Bs[lq*4+2][lr] = b0.z; Bs[lq*4+3][lr] = b0.w;
    Bs[lq*4+0][lr+64] = b1.x; Bs[lq*4+1][lr+64] = b1.y; Bs[lq*4+2][lr+64] = b1.z; Bs[lq*4+3][lr+64] = b1.w;
    __syncthreads();
    #pragma unroll
    for (int k=0;k<16;k++){
      float4 va0 = *(const float4*)&As[k][tmr*8];
      float4 va1 = *(const float4*)&As[k][tmr*8+4];
      float4 vb0 = *(const float4*)&Bs[k][tnr*8];
      float4 vb1 = *(const float4*)&Bs[k][tnr*8+4];
      float av[8] = {va0.x,va0.y,va0.z,va0.w,va1.x,va1.y,va1.z,va1.w};
      float bv[8] = {vb0.x,vb0.y,vb0.z,vb0.w,vb1.x,vb1.y,vb1.z,vb1.w};
      #pragma unroll
      for (int i=0;i<8;i++){
        #pragma unroll
        for (int j=0;j<8;j++) acc[i][j] = fmaf(av[i], bv[j], acc[i][j]);
      }
    }
  }
  size_t crow = (size_t)blockIdx.y * mstr;
  #pragma unroll
  for (int i=0;i<8;i++){
    int m = tm0 + tmr*8 + i;
    float4 c0 = make_float4(acc[i][0],acc[i][1],acc[i][2],acc[i][3]);
    float4 c1 = make_float4(acc[i][4],acc[i][5],acc[i][6],acc[i][7]);
    *(float4*)&Cp[(crow + m)*(size_t)ldc + tn0 + tnr*8]     = c0;
    *(float4*)&Cp[(crow + m)*(size_t)ldc + tn0 + tnr*8 + 4] = c1;
  }
}

__global__ __launch_bounds__(256) void combine_k(const float* Cp, const float* bias, float* out,
                                                 int M, int N, int ldc, int mstr, int nsp, int relu){
  int g = blockIdx.x*256 + threadIdx.x;
  if (g >= M*N) return;
  int m = g / N, n = g - m*N;
  float s = bias[n];
  for (int sp=0; sp<nsp; sp++) s += Cp[((size_t)sp*mstr + m)*(size_t)ldc + n];
  if (relu) s = fmaxf(s, 0.f);
  out[(size_t)m*N + n] = s;
}

__global__ __launch_bounds__(256) void combine_head_k(const float* Cp, const float* BCAT,
                                                      float* LG2, float* RG2){
  int g = blockIdx.x*256 + threadIdx.x;
  if (g >= 2000*401) return;
  int m = g / 401, n = g - m*401;
  float s = BCAT[n];
  #pragma unroll
  for (int sp=0; sp<4; sp++) s += Cp[((size_t)sp*2048 + m)*512 + n];
  if (n < 81) LG2[m*81 + n] = s;
  else        RG2[(size_t)m*320 + (n-81)] = s;
}

// ------------------------------------------------------------------ stage-2 softmax + key gen
__global__ __launch_bounds__(64) void softmax_key_k(const float* LG2, const u32* PVALID, u32* KEY2){
  int r = blockIdx.x;
  int lane = threadIdx.x;
  const float* lp = &LG2[r*81];
  float v0 = lp[lane];
  float v1 = (lane < 17) ? lp[64+lane] : -3.4e38f;
  float m = fmaxf(v0, v1);
  #pragma unroll
  for (int o=32; o; o>>=1) m = fmaxf(m, __shfl_xor(m, o, 64));
  float e0 = expf(v0 - m);
  float e1 = (lane < 17) ? expf(v1 - m) : 0.f;
  float sm = e0 + e1;
  #pragma unroll
  for (int o=32; o; o>>=1) sm += __shfl_xor(sm, o, 64);
  u32 valid = PVALID[r];
  float s0 = e0 / sm;
  KEY2[r*80 + lane] = (valid && s0 > 0.05f) ? fkey(s0) : 0;   // lane<64 => class<80
  if (lane < 16){
    float s1 = e1 / sm;
    KEY2[r*80 + 64 + lane] = (valid && s1 > 0.05f) ? fkey(s1) : 0;
  }
}

// ------------------------------------------------------------------ stage-2 decode + NMS + output
__global__ __launch_bounds__(256) void decode2_k(const u64* SEL2, const float* RG2, const float* PROPS,
    const int* imsz, float* B2, float* TOPS, int* RIDX, int* CLS2, int* GRP2, u64* VMASK){
  int g = blockIdx.x*256 + threadIdx.x;
  u64 e = SEL2[g];
  bool valid = (e >> 32) != 0ull;
  float tops = -1.f;
  int ridx = 0, cls = 0;
  float4 b = make_float4(0,0,0,0);
  if (valid){
    u32 key = (u32)(e >> 32);
    u32 idx = ~((u32)e);
    ridx = (int)(idx / 80u);
    cls  = (int)(idx - (u32)ridx*80u);
    tops = keyinv(key);
    const float* rg = &RG2[(size_t)ridx*320 + cls*4];
    float4 p = *(const float4*)&PROPS[(size_t)ridx*4];
    float pw = p.z-p.x, ph = p.w-p.y;
    float pcx = p.x+0.5f*pw, pcy = p.y+0.5f*ph;
    float cx = pcx + (rg[0]*0.1f)*pw;
    float cy = pcy + (rg[1]*0.1f)*ph;
    float w  = pw * expf(fminf(rg[2]*0.2f, BBOX_CLAMP));
    float h  = ph * expf(fminf(rg[3]*0.2f, BBOX_CLAMP));
    int im = ridx / 1000;
    float Wc = (float)imsz[im*2+1], Hc = (float)imsz[im*2+0];
    b.x = fminf(fmaxf(cx-0.5f*w, 0.f), Wc);
    b.y = fminf(fmaxf(cy-0.5f*h, 0.f), Hc);
    b.z = fminf(fmaxf(cx+0.5f*w, 0.f), Wc);
    b.w = fminf(fmaxf(cy+0.5f*h, 0.f), Hc);
  }
  int im = ridx / 1000;
  *(float4*)&B2[(size_t)g*4] = b;
  TOPS[g] = tops;
  RIDX[g] = ridx;
  CLS2[g] = cls;
  GRP2[g] = im*80 + cls;
  u64 mask = __ballot(valid);
  if ((threadIdx.x & 63) == 0) VMASK[g >> 6] = mask;
}

__global__ __launch_bounds__(256) void nms_mat2_k(const float* B2, const int* GRP2, u64* MAT2){
  int i = blockIdx.x*4 + (threadIdx.x >> 6);
  int w = threadIdx.x & 63;
  float4 bi = *(const float4*)&B2[(size_t)i*4];
  float offi = (float)GRP2[i] * 4096.0f;
  bi.x += offi; bi.y += offi; bi.z += offi; bi.w += offi;
  float ai = (bi.z-bi.x)*(bi.w-bi.y);
  u64 bits = 0;
  #pragma unroll 4
  for (int u=0; u<64; u++){
    int j = w*64 + u;
    if (j > i){
      float4 bj = *(const float4*)&B2[(size_t)j*4];
      float offj = (float)GRP2[j] * 4096.0f;
      bj.x += offj; bj.y += offj; bj.z += offj; bj.w += offj;
      float aj = (bj.z-bj.x)*(bj.w-bj.y);
      float lx = fmaxf(bi.x,bj.x), ly = fmaxf(bi.y,bj.y);
      float rx = fminf(bi.z,bj.z), ry = fminf(bi.w,bj.w);
      float iw = fmaxf(rx-lx,0.f), ih = fmaxf(ry-ly,0.f);
      float inter = iw*ih;
      float iou = inter / fmaxf(ai+aj-inter, 1e-9f);
      if (iou > 0.5f) bits |= (1ull<<u);
    }
  }
  MAT2[(size_t)i*64 + w] = bits;
}

__global__ __launch_bounds__(64) void nms_scan2_k(const u64* MAT2, const int* GRP2, const u64* VMASK,
                                                  u32* KEEP2){
  int g = blockIdx.x;
  int lane = threadIdx.x;
  __shared__ u16 listi[4096];
  u64 aw = VMASK[lane];
  int n = 0;
  for (int ch=0; ch<64; ch++){
    int i = ch*64 + lane;
    bool m = (GRP2[i] == g);
    u64 bal = __ballot(m);
    if (m){
      int pos = n + (int)__popcll(bal & lanemask_lt(lane));
      listi[pos] = (u16)i;
    }
    n += (int)__popcll(bal);
  }
  __syncthreads();
#define LDR2(p) (((p) < n) ? MAT2[(size_t)listi[(p)]*64 + lane] : 0ull)
  u64 q0=LDR2(0),q1=LDR2(1),q2=LDR2(2),q3=LDR2(3),q4=LDR2(4),q5=LDR2(5),q6=LDR2(6),q7=LDR2(7);
  for (int p=0; p<n; p++){
    u64 cur = q0; q0=q1; q1=q2; q2=q3; q3=q4; q4=q5; q5=q6; q6=q7; q7=LDR2(p+8);
    int i = listi[p];
    u64 wv = __shfl(aw, i>>6, 64);
    bool alive = (wv >> (i & 63)) & 1ull;
    aw &= ~(alive ? cur : 0ull);
  }
#undef LDR2
  __syncthreads();
  for (int ch=0; ch<64; ch++){
    int i = ch*64 + lane;
    u64 wv = __shfl(aw, ch, 64);
    if (GRP2[i] == g) KEEP2[i] = (u32)((wv >> lane) & 1ull);
  }
}

__global__ __launch_bounds__(64) void out_fill_k(const u32* KEEP2, const int* RIDX, const int* CLS2,
    const float* B2, const float* TOPS, float* OUT){
  int img = blockIdx.x;
  int lane = threadIdx.x;
  int cnt = 0;
  for (int ch=0; ch<64; ch++){
    if (cnt >= 100) break;
    int i = ch*64 + lane;
    bool k = (KEEP2[i] != 0) && ((RIDX[i]/1000) == img);
    u64 bal = __ballot(k);
    if (k){
      int pos = cnt + (int)__popcll(bal & lanemask_lt(lane));
      if (pos < 100){
        float4 b = *(const float4*)&B2[(size_t)i*4];
        OUT[img*400 + pos*4 + 0] = b.x;
        OUT[img*400 + pos*4 + 1] = b.y;
        OUT[img*400 + pos*4 + 2] = b.z;
        OUT[img*400 + pos*4 + 3] = b.w;
        OUT[800 + img*100 + pos]  = TOPS[i];
        OUT[1000 + img*100 + pos] = (float)CLS2[i];
      }
    }
    cnt += (int)__popcll(bal);
  }
  if (cnt > 100) cnt = 100;
  for (int s = cnt + lane; s < 100; s += 64){
    OUT[img*400 + s*4 + 0] = 0.f;
    OUT[img*400 + s*4 + 1] = 0.f;
    OUT[img*400 + s*4 + 2] = 0.f;
    OUT[img*400 + s*4 + 3] = 0.f;
    OUT[800 + img*100 + s]  = 0.f;
    OUT[1000 + img*100 + s] = -1.f;
  }
}

// ==================================================================
static inline size_t algn(size_t x){ return (x + 255) & ~(size_t)255; }

extern "C" void kernel_launch(void* const* d_in, const int* in_sizes, int n_in,
                              void* d_out, int out_size, void* d_ws, size_t ws_size,
                              hipStream_t stream) {
  (void)in_sizes; (void)n_in;
  const float* fmap[5]; const float* pri[5];
  for (int i=0;i<5;i++){ fmap[i] = (const float*)d_in[i]; pri[i] = (const float*)d_in[5+i]; }
  const int*   imsz  = (const int*)d_in[10];
  const float* rpnw  = (const float*)d_in[11];
  const float* rpnb  = (const float*)d_in[12];
  const float* logw  = (const float*)d_in[13];
  const float* logb  = (const float*)d_in[14];
  const float* regw  = (const float*)d_in[15];
  const float* regb  = (const float*)d_in[16];
  const float* fc1w  = (const float*)d_in[17];
  const float* fc1b  = (const float*)d_in[18];
  const float* fc2w  = (const float*)d_in[19];
  const float* fc2b  = (const float*)d_in[20];
  const float* clsw  = (const float*)d_in[21];
  const float* clsb  = (const float*)d_in[22];
  const float* bregw = (const float*)d_in[23];
  const float* bregb = (const float*)d_in[24];
  float* OUT = (float*)d_out;

  // ---- workspace layout (chunked stage-2: ~74 MB total instead of ~166 MB)
  size_t o = 0;
  auto A = [&](size_t b)->size_t{ size_t r = o; o = algn(o + b); return r; };
  size_t oHISTA = A(16*4096*4);
  size_t oHISTB = A(16*4096*4);
  size_t oCNT   = A(256);
  size_t zone1_end = o;
  size_t oSCANB = A(16*16*4);
  size_t oPROPS = A(2000*16);
  size_t oPVAL  = A(2000*4);
  size_t zone2_end = o;
  size_t oWT    = A((size_t)2304*256*4);
  size_t oLOGIT = A((size_t)212784*4);
  size_t oREG   = A((size_t)212784*16);
  size_t oKEY1  = A((size_t)212784*4);
  size_t oKEY2  = A((size_t)160000*4);
  size_t oCAND  = A((size_t)(10*2048+8192)*8);
  size_t oSEL   = A((size_t)(10*1024+4096)*8);
  size_t oBOX1  = A((size_t)10*1024*16);
  size_t oSC1   = A((size_t)10*1024*4);
  size_t oKEEPM = A((size_t)10*16*8);
  size_t oKPRE  = A((size_t)10*1056*4);
  size_t oMAT1  = A((size_t)10*1024*16*8);
  size_t oH1    = A((size_t)2000*1024*4);
  size_t oH2    = A((size_t)2000*1024*4);
  // union buffer: {FEATC 500x12544 f32 (25.1MB) + GPC 8x512x1024 f32 (16.8MB)}
  //            vs {GP_full 4x2048x1024 f32 (33.6MB)} — never live simultaneously
  size_t featc_b = (size_t)500*12544*4;            // 25,088,000
  size_t gpc_b   = (size_t)8*512*1024*4;           // 16,777,216
  size_t gpf_b   = (size_t)4*2048*1024*4;          // 33,554,432
  size_t ub_b    = featc_b + gpc_b;                // 41,865,216 > gpf_b
  size_t oUB    = A(ub_b);
  size_t oWCAT  = A((size_t)401*1024*4);
  size_t oBCAT  = A((size_t)401*4);
  size_t oLG2   = A((size_t)2000*81*4);
  size_t oRG2   = A((size_t)2000*320*4);
  size_t oB2    = A((size_t)4096*16);
  size_t oTOPS  = A((size_t)4096*4);
  size_t oRIDX  = A((size_t)4096*4);
  size_t oCLS2  = A((size_t)4096*4);
  size_t oGRP2  = A((size_t)4096*4);
  size_t oVM    = A((size_t)64*8);
  size_t oKEEP2 = A((size_t)4096*4);
  size_t oMAT2  = A((size_t)4096*64*8);

  // ---- ws_size guard: if scratch is too small, emit zeros (diagnosable as
  // "incorrect" instead of crashing the container with OOB writes).
  if (ws_size < o){
    hipMemsetAsync(d_out, 0, (size_t)out_size*4, stream);
    return;
  }

  char* W = (char*)d_ws;
  float* WT    = (float*)(W+oWT);
  float* LOGIT = (float*)(W+oLOGIT);
  float* REGB  = (float*)(W+oREG);
  u32*   KEY1  = (u32*)(W+oKEY1);
  u32*   KEY2  = (u32*)(W+oKEY2);
  u32*   HISTA = (u32*)(W+oHISTA);
  u32*   HISTB = (u32*)(W+oHISTB);
  u32*   CNT   = (u32*)(W+oCNT);
  u32*   SCANB = (u32*)(W+oSCANB);
  u64*   CAND  = (u64*)(W+oCAND);
  u64*   SEL   = (u64*)(W+oSEL);
  float* BOX1  = (float*)(W+oBOX1);
  float* SC1   = (float*)(W+oSC1);
  u64*   KEEPM = (u64*)(W+oKEEPM);
  u32*   KPRE  = (u32*)(W+oKPRE);
  u64*   MAT1  = (u64*)(W+oMAT1);
  float* PROPS = (float*)(W+oPROPS);
  u32*   PVAL  = (u32*)(W+oPVAL);
  float* H1    = (float*)(W+oH1);
  float* H2    = (float*)(W+oH2);
  float* FEATC = (float*)(W+oUB);
  float* GPC   = (float*)(W+oUB+featc_b);
  float* GP    = (float*)(W+oUB);
  float* WCAT  = (float*)(W+oWCAT);
  float* BCAT  = (float*)(W+oBCAT);
  float* LG2   = (float*)(W+oLG2);
  float* RG2   = (float*)(W+oRG2);
  float* B2    = (float*)(W+oB2);
  float* TOPS  = (float*)(W+oTOPS);
  int*   RIDX  = (int*)(W+oRIDX);
  int*   CLS2  = (int*)(W+oCLS2);
  int*   GRP2  = (int*)(W+oGRP2);
  u64*   VMASK = (u64*)(W+oVM);
  u32*   KEEP2 = (u32*)(W+oKEEP2);
  u64*   MAT2  = (u64*)(W+oMAT2);

  // ---- tables
  static const int Hs[5]={128,64,32,16,8}, Ws[5]={208,104,52,26,13};
  static const int TXs[5]={8,4,2,1,1};
  static const int bases[5]={0,2048,2560,2688,2720};
  static const int szl[5]={79872,19968,4992,1248,312};
  static const int loff[5]={0,159744,199680,209664,212160};
  static const int kls[5]={1000,1000,1000,1000,312};
  ConvTab ct;
  for (int l=0;l<5;l++){ ct.fm[l]=fmap[l]; ct.H[l]=Hs[l]; ct.W[l]=Ws[l]; ct.TX[l]=TXs[l];
                         ct.base[l]=bases[l]; ct.loff[l]=loff[l]; ct.szl[l]=szl[l]; }
  PriTab pt; for (int l=0;l<5;l++) pt.p[l]=pri[l];
  RoiTab rt;
  for (int l=0;l<4;l++){ rt.fm[l]=fmap[l]; rt.H[l]=Hs[l]; rt.W[l]=Ws[l]; }
  rt.inv[0]=0.25f; rt.inv[1]=0.125f; rt.inv[2]=0.0625f; rt.inv[3]=0.03125f;
  SelTab st;
  for (int l=0;l<5;l++) for (int im=0; im<2; im++){
    int li = l*2+im;
    st.d[li].key_off = loff[l] + im*szl[l];
    st.d[li].size = szl[l];
    st.d[li].k = kls[l];
    st.d[li].cand_off = li*2048;
    st.d[li].cand_cap = 2048;
    st.d[li].cnt_idx = li;
    st.d[li].sel_off = li*1024;
  }
  st.d[10].key_off=0; st.d[10].size=160000; st.d[10].k=4096;
  st.d[10].cand_off=20480; st.d[10].cand_cap=8192; st.d[10].cnt_idx=10; st.d[10].sel_off=10240;

  // ---- zero control regions
  hipMemsetAsync(W+oHISTA, 0, zone1_end - oHISTA, stream);
  hipMemsetAsync(W+oPROPS, 0, zone2_end - oPROPS, stream);

  // ---- stage 1: RPN
  prep_wt_k<<<2304,256,0,stream>>>(rpnw, WT);
  prep_wcat_k<<<1604,256,0,stream>>>(clsw, clsb, bregw, bregb, WCAT, BCAT);
  rpn_fused_k<<<2736,256,0,stream>>>(ct, WT, rpnb, logw, logb, regw, regb, LOGIT, REGB);
  keygen1_k<<<832,256,0,stream>>>(LOGIT, KEY1);

  hist_k<<<dim3(20,10),256,0,stream>>>(KEY1, HISTA, SCANB, st, 0, 1);
  scan_k<<<10,256,0,stream>>>(HISTA, SCANB, st, 0, 1);
  hist_k<<<dim3(20,10),256,0,stream>>>(KEY1, HISTB, SCANB, st, 0, 2);
  scan_k<<<10,256,0,stream>>>(HISTB, SCANB, st, 0, 2);
  compact_k<<<dim3(20,10),256,0,stream>>>(KEY1, SCANB, CAND, CNT, st, 0);
  sort_k<<<10,256,0,stream>>>(CAND, CNT, SEL, st, 0);
  decode1_k<<<40,256,0,stream>>>(SEL, LOGIT, REGB, pt, imsz, st, BOX1, SC1);
  nms_mat1_k<<<dim3(63,10),256,0,stream>>>(BOX1, MAT1);
  nms_scan1_k<<<10,64,0,stream>>>(MAT1, KEEPM);
  kprefix_k<<<10,64,0,stream>>>(KEEPM, KPRE);
  merge_k<<<40,256,0,stream>>>(KEEPM, KPRE, SC1, BOX1, PROPS, PVAL);

  // ---- stage 2: chunked ROI align + fc1 (4 chunks of 500 ROIs, split-K=8)
  for (int c=0; c<4; c++){
    roi_align_k<<<500,256,0,stream>>>(rt, PROPS, FEATC, c*500);
    gemm_k<<<dim3(32,8),256,0,stream>>>(FEATC, 12544, 500, fc1w, 12544, 1024, GPC, 1024, 1568, 4, 512);
    combine_k<<<2000,256,0,stream>>>(GPC, fc1b, H1 + (size_t)c*500*1024, 500, 1024, 1024, 512, 8, 1);
  }
  // fc2 + heads on full M=2000 (GP reuses the FEATC/GPC union region)
  gemm_k<<<dim3(128,4),256,0,stream>>>(H1, 1024, 2000, fc2w, 1024, 1024, GP, 1024, 256, 16, 2048);
  combine_k<<<8000,256,0,stream>>>(GP, fc2b, H2, 2000, 1024, 1024, 2048, 4, 1);
  gemm_k<<<dim3(64,4),256,0,stream>>>(H2, 1024, 2000, WCAT, 1024, 401, GP, 512, 256, 16, 2048);
  combine_head_k<<<3134,256,0,stream>>>(GP, BCAT, LG2, RG2);

  softmax_key_k<<<2000,64,0,stream>>>(LG2, PVAL, KEY2);

  // ---- stage-2 top-4096 select
  hipMemsetAsync(W+oHISTA, 0, zone1_end - oHISTA, stream);
  hist_k<<<dim3(40,1),256,0,stream>>>(KEY2, HISTA, SCANB, st, 10, 1);
  scan_k<<<1,256,0,stream>>>(HISTA, SCANB, st, 10, 1);
  hist_k<<<dim3(40,1),256,0,stream>>>(KEY2, HISTB, SCANB, st, 10, 2);
  scan_k<<<1,256,0,stream>>>(HISTB, SCANB, st, 10, 2);
  compact_k<<<dim3(40,1),256,0,stream>>>(KEY2, SCANB, CAND, CNT, st, 10);
  sort_k<<<1,256,0,stream>>>(CAND, CNT, SEL, st, 10);

  decode2_k<<<16,256,0,stream>>>(SEL + 10240, RG2, PROPS, imsz, B2, TOPS, RIDX, CLS2, GRP2, VMASK);
  nms_mat2_k<<<1024,256,0,stream>>>(B2, GRP2, MAT2);
  nms_scan2_k<<<160,64,0,stream>>>(MAT2, GRP2, VMASK, KEEP2);
  out_fill_k<<<2,64,0,stream>>>(KEEP2, RIDX, CLS2, B2, TOPS, OUT);
}